// Round 2
// baseline (273.262 us; speedup 1.0000x reference)
//
#include <hip/hip_runtime.h>

// B=8, S=256, C=256, V=64 — fp32 inputs/outputs, fp16 MFMA internally.
// out[b,s,z,k] = tanh( BIL + r[b,z,k] + t[b,s,k] )
//   W_eff[i,j,k] = W[i,j,k] + (i==j)*linmul_w[k,j]
//   tmp[(b,s)][k][j] = sum_i ctx[b,s,i] * W_eff[i,j,k]          (GEMM1, n'=k*256+j)
//   BIL[b,s,z,k]     = sum_j ctx[b,z,j] * tmp[(b,s)][k][j]      (GEMM2)
//   r[b,z,k] = ctx[b,z,:]·(lin1_w[k,:]+lindiff_w[k,:]) + lin1_b[k]
//   t[b,s,k] = ctx[b,s,:]·(lin2_w[k,:]-lindiff_w[k,:]) + lin2_b[k]
//              + bias[k] + linmul_b[k] + lindiff_b[k]

typedef __attribute__((ext_vector_type(8))) _Float16 half8;
typedef __attribute__((ext_vector_type(4))) _Float16 half4v;
typedef __attribute__((ext_vector_type(4))) float f32x4;

__device__ __forceinline__ void async16(const void* g, void* l) {
  __builtin_amdgcn_global_load_lds(
      (__attribute__((address_space(1))) void*)g,
      (__attribute__((address_space(3))) void*)l, 16, 0, 0);
}

// ---- prep 0: ctx fp32 -> fp16 ----
__global__ __launch_bounds__(256) void prep_ctx(const float* __restrict__ ctx,
                                                _Float16* __restrict__ ch) {
  int idx = (blockIdx.x * 256 + threadIdx.x) * 4;
  float4 v = *(const float4*)(ctx + idx);
  half4v o;
  o[0] = (_Float16)v.x; o[1] = (_Float16)v.y;
  o[2] = (_Float16)v.z; o[3] = (_Float16)v.w;
  *(half4v*)(ch + idx) = o;
}

// ---- prep 1: wt[n'=(k*256+j)][i] = fp16( W[i][j][k] + (i==j)*lmw[k*256+j] ) ----
// one block per j
__global__ __launch_bounds__(256) void prep_wt(const float* __restrict__ W,
                                               const float* __restrict__ lmw,
                                               _Float16* __restrict__ wt) {
  __shared__ _Float16 T[256 * 68];  // [i][k], pad 64->68
  const int t = threadIdx.x;
  const int j = blockIdx.x;
#pragma unroll
  for (int p = 0; p < 16; ++p) {
    int i = p * 16 + (t >> 4);
    int c = t & 15;  // float4 chunk along k
    float4 v = *(const float4*)&W[(size_t)i * 16384 + j * 64 + c * 4];
    if (i == j) {
      v.x += lmw[(c * 4 + 0) * 256 + j];
      v.y += lmw[(c * 4 + 1) * 256 + j];
      v.z += lmw[(c * 4 + 2) * 256 + j];
      v.w += lmw[(c * 4 + 3) * 256 + j];
    }
    half4v o;
    o[0] = (_Float16)v.x; o[1] = (_Float16)v.y;
    o[2] = (_Float16)v.z; o[3] = (_Float16)v.w;
    *(half4v*)&T[i * 68 + c * 4] = o;
  }
  __syncthreads();
  const int k = t >> 2, i0 = (t & 3) * 64;
  _Float16* dst = wt + ((size_t)(k * 256 + j)) * 256 + i0;
#pragma unroll
  for (int u = 0; u < 64; u += 8) {
    half8 o;
#pragma unroll
    for (int e = 0; e < 8; ++e) o[e] = T[(i0 + u + e) * 68 + k];
    *(half8*)(dst + u) = o;
  }
}

// ---- prep 2: r[row][k], t[row][k] fp32 (row = b*256+s) ----
__global__ __launch_bounds__(256) void prep_rt(
    const float* __restrict__ ctx, const float* __restrict__ bias,
    const float* __restrict__ l1w, const float* __restrict__ l1b,
    const float* __restrict__ l2w, const float* __restrict__ l2b,
    const float* __restrict__ lmb, const float* __restrict__ ldw,
    const float* __restrict__ ldb, float* __restrict__ rbuf,
    float* __restrict__ tbuf) {
  __shared__ float Cs[4 * 256];
  const int t = threadIdx.x;
  const int row0 = blockIdx.x * 4;
  ((float4*)Cs)[t] = ((const float4*)(ctx + (size_t)row0 * 256))[t];
  __syncthreads();
  const int k = t & 63, lr = t >> 6;
  const float* l1r = l1w + k * 256;
  const float* l2r = l2w + k * 256;
  const float* ldr = ldw + k * 256;
  float a1 = 0.f, a2 = 0.f;
  for (int c = 0; c < 256; c += 4) {
    float4 w1 = *(const float4*)(l1r + c);
    float4 w2 = *(const float4*)(l2r + c);
    float4 wd = *(const float4*)(ldr + c);
    float4 cv = *(const float4*)(&Cs[lr * 256 + c]);
    a1 += cv.x * (w1.x + wd.x) + cv.y * (w1.y + wd.y) +
          cv.z * (w1.z + wd.z) + cv.w * (w1.w + wd.w);
    a2 += cv.x * (w2.x - wd.x) + cv.y * (w2.y - wd.y) +
          cv.z * (w2.z - wd.z) + cv.w * (w2.w - wd.w);
  }
  int row = row0 + lr;
  rbuf[row * 64 + k] = a1 + l1b[k];
  tbuf[row * 64 + k] = a2 + l2b[k] + bias[k] + lmb[k] + ldb[k];
}

// ---- GEMM1: tmp[m][n'] = ctx_h[m][:] . wt[n'][:]  (M=2048, N=16384, K=256) ----
__global__ __launch_bounds__(256) void gemm1(const _Float16* __restrict__ ch,
                                             const _Float16* __restrict__ wt,
                                             _Float16* __restrict__ tmp) {
  __shared__ _Float16 As[128 * 32];
  __shared__ _Float16 Bs[128 * 32];
  const int t = threadIdx.x;
  const int lane = t & 63, wave = t >> 6;
  const int m0 = blockIdx.y * 128, n0 = blockIdx.x * 128;
  const int wm = (wave & 1) * 64, wn = (wave >> 1) * 64;
  const int r = lane & 15, q = lane >> 4;
  f32x4 acc[4][4] = {};
  const _Float16* gA = ch + (size_t)(m0 + (t >> 2)) * 256 + (t & 3) * 8;
  const _Float16* gB = wt + (size_t)(n0 + (t >> 2)) * 256 + (t & 3) * 8;
  for (int k0 = 0; k0 < 256; k0 += 32) {
    async16(gA + k0, &As[t * 8]);
    async16(gA + 64 * 256 + k0, &As[2048 + t * 8]);
    async16(gB + k0, &Bs[t * 8]);
    async16(gB + 64 * 256 + k0, &Bs[2048 + t * 8]);
    __syncthreads();
    half8 a[4], b[4];
#pragma unroll
    for (int mi = 0; mi < 4; ++mi)
      a[mi] = *(const half8*)&As[(wm + mi * 16 + r) * 32 + q * 8];
#pragma unroll
    for (int ni = 0; ni < 4; ++ni)
      b[ni] = *(const half8*)&Bs[(wn + ni * 16 + r) * 32 + q * 8];
#pragma unroll
    for (int mi = 0; mi < 4; ++mi)
#pragma unroll
      for (int ni = 0; ni < 4; ++ni)
        acc[mi][ni] = __builtin_amdgcn_mfma_f32_16x16x32_f16(a[mi], b[ni],
                                                             acc[mi][ni], 0, 0, 0);
    __syncthreads();
  }
#pragma unroll
  for (int mi = 0; mi < 4; ++mi)
#pragma unroll
    for (int ni = 0; ni < 4; ++ni) {
      int m = m0 + wm + mi * 16 + q * 4;
      int n = n0 + wn + ni * 16 + r;
#pragma unroll
      for (int e = 0; e < 4; ++e)
        tmp[(size_t)(m + e) * 16384 + n] = (_Float16)acc[mi][ni][e];
    }
}

// ---- GEMM2 + epilogue: block per (b,s); out[z][k] = tanh(ctx_b @ tmp_bs^T + r + t) ----
__global__ __launch_bounds__(256) void gemm2(const _Float16* __restrict__ ch,
                                             const _Float16* __restrict__ tmp,
                                             const float* __restrict__ rbuf,
                                             const float* __restrict__ tbuf,
                                             float* __restrict__ out) {
  __shared__ _Float16 As[256 * 32];  // ctx_b [z][j-chunk]
  __shared__ _Float16 Bs[64 * 32];   // tmp_bs [k][j-chunk] (already transposed!)
  __shared__ float Ts[64];
  const int t = threadIdx.x;
  const int lane = t & 63, wave = t >> 6;
  const int bs = blockIdx.x;
  const int b = bs >> 8;
  const int r = lane & 15, q = lane >> 4;
  const _Float16* ctxb = ch + (size_t)b * 65536;
  const _Float16* tm = tmp + (size_t)bs * 16384;
  if (t < 64) Ts[t] = tbuf[bs * 64 + t];
  f32x4 acc[4][4] = {};
  for (int j0 = 0; j0 < 256; j0 += 32) {
#pragma unroll
    for (int p = 0; p < 4; ++p)
      async16(ctxb + (size_t)(p * 64 + (t >> 2)) * 256 + j0 + (t & 3) * 8,
              &As[p * 2048 + t * 8]);
    async16(tm + (size_t)(t >> 2) * 256 + j0 + (t & 3) * 8, &Bs[t * 8]);
    __syncthreads();
    half8 a[4], bf[4];
#pragma unroll
    for (int mi = 0; mi < 4; ++mi)
      a[mi] = *(const half8*)&As[(wave * 64 + mi * 16 + r) * 32 + q * 8];
#pragma unroll
    for (int ni = 0; ni < 4; ++ni)
      bf[ni] = *(const half8*)&Bs[(ni * 16 + r) * 32 + q * 8];
#pragma unroll
    for (int mi = 0; mi < 4; ++mi)
#pragma unroll
      for (int ni = 0; ni < 4; ++ni)
        acc[mi][ni] = __builtin_amdgcn_mfma_f32_16x16x32_f16(a[mi], bf[ni],
                                                             acc[mi][ni], 0, 0, 0);
    __syncthreads();
  }
  const float* rb = rbuf + (size_t)b * 16384;
#pragma unroll
  for (int mi = 0; mi < 4; ++mi)
#pragma unroll
    for (int ni = 0; ni < 4; ++ni) {
      int z0 = wave * 64 + mi * 16 + q * 4;
      int k = ni * 16 + r;
#pragma unroll
      for (int e = 0; e < 4; ++e) {
        int z = z0 + e;
        float x = acc[mi][ni][e] + rb[z * 64 + k] + Ts[k];
        float ax = fabsf(x);
        float ev = __expf(-2.0f * ax);
        float y = (1.0f - ev) / (1.0f + ev);
        y = copysignf(y, x);
        out[((size_t)bs * 256 + z) * 64 + k] = y;
      }
    }
}

extern "C" void kernel_launch(void* const* d_in, const int* in_sizes, int n_in,
                              void* d_out, int out_size, void* d_ws, size_t ws_size,
                              hipStream_t stream) {
  const float* ctx  = (const float*)d_in[0];
  const float* W    = (const float*)d_in[1];
  const float* bias = (const float*)d_in[2];
  const float* l1w  = (const float*)d_in[3];
  const float* l1b  = (const float*)d_in[4];
  const float* l2w  = (const float*)d_in[5];
  const float* l2b  = (const float*)d_in[6];
  const float* lmw  = (const float*)d_in[7];
  const float* lmb  = (const float*)d_in[8];
  const float* ldw  = (const float*)d_in[9];
  const float* ldb  = (const float*)d_in[10];
  float* out = (float*)d_out;

  char* ws = (char*)d_ws;
  _Float16* ch  = (_Float16*)ws;                               // 1 MiB ctx fp16
  _Float16* wt  = (_Float16*)(ws + (1u << 20));                // 8 MiB W_eff^T fp16
  _Float16* tmp = (_Float16*)(ws + (9u << 20));                // 64 MiB tmp fp16
  float* rbuf = (float*)(ws + (73u << 20));                    // 512 KiB
  float* tbuf = rbuf + 2048 * 64;                              // 512 KiB

  prep_ctx<<<512, 256, 0, stream>>>(ctx, ch);
  prep_wt<<<256, 256, 0, stream>>>(W, lmw, wt);
  prep_rt<<<512, 256, 0, stream>>>(ctx, bias, l1w, l1b, l2w, l2b, lmb, ldw, ldb,
                                   rbuf, tbuf);
  gemm1<<<dim3(128, 16), 256, 0, stream>>>(ch, wt, tmp);
  gemm2<<<2048, 256, 0, stream>>>(ch, tmp, rbuf, tbuf, out);
}